// Round 3
// baseline (423.712 us; speedup 1.0000x reference)
//
#include <hip/hip_runtime.h>

// Problem constants (fixed shape)
// N=8192 tokens, D=1280, H=16 heads, K=80 head dim (pad 96), S=16 segs, L=512
#define LOG2E 1.44269504088896340736f
#define ATT_SCALE 0.11180339887498949f  // 80^-0.5

typedef _Float16 half8 __attribute__((ext_vector_type(8)));
typedef _Float16 half4v __attribute__((ext_vector_type(4)));
typedef __fp16 fp16x2 __attribute__((ext_vector_type(2)));
typedef float f32x4 __attribute__((ext_vector_type(4)));

#define MFMA(a, b, c) __builtin_amdgcn_mfma_f32_16x16x32_f16((a), (b), (c), 0, 0, 0)

__device__ __forceinline__ void async16(const _Float16* g, _Float16* l) {
  __builtin_amdgcn_global_load_lds(
      (const __attribute__((address_space(1))) unsigned int*)g,
      (__attribute__((address_space(3))) unsigned int*)l,
      16, 0, 0);
}

#define FENCE() asm volatile("" ::: "memory")
// phase boundary: raw barrier, pinned against compiler motion on both sides
#define PHB()                                   \
  do {                                          \
    __builtin_amdgcn_sched_barrier(0);          \
    FENCE();                                    \
    __builtin_amdgcn_s_barrier();               \
    FENCE();                                    \
    __builtin_amdgcn_sched_barrier(0);          \
  } while (0)

// ---------------- fp32 -> fp16 convert (hidden) ----------------
__global__ __launch_bounds__(256) void cvt_k(const float* __restrict__ in,
                                             _Float16* __restrict__ out, int n4) {
  int i = blockIdx.x * 256 + threadIdx.x;
  if (i < n4) {
    f32x4 v = ((const f32x4*)in)[i];
    half4v hv;
    hv[0] = (_Float16)v[0]; hv[1] = (_Float16)v[1];
    hv[2] = (_Float16)v[2]; hv[3] = (_Float16)v[3];
    ((half4v*)out)[i] = hv;
  }
}

// ---------------- transpose + convert: in R x C fp32 -> out C x R fp16 ----------
__global__ __launch_bounds__(256) void transpose_cvt_k(const float* __restrict__ in,
                                                       _Float16* __restrict__ out,
                                                       int R, int C) {
  __shared__ float tile[32][33];
  const int tx = threadIdx.x & 31, ty = threadIdx.x >> 5;
  const int c0 = blockIdx.x * 32, r0 = blockIdx.y * 32;
#pragma unroll
  for (int i = 0; i < 32; i += 8)
    tile[ty + i][tx] = in[(size_t)(r0 + ty + i) * C + c0 + tx];
  __syncthreads();
#pragma unroll
  for (int i = 0; i < 32; i += 8)
    out[(size_t)(c0 + ty + i) * R + r0 + tx] = (_Float16)tile[tx][ty + i];
}

// ---------------- GEMM0: 256x256 tile, BK=64, pipelined 4-phase K-loop --------
// C = A(8192x1280) * BT^T (3840x1280), scatter epilogue -> Qf/Kf/VTf
//
// Round-3 structure: 1 block/CU (128 KB LDS), so the lever is INTRA-wave
// overlap of the LDS-read stream (~2200 cyc/K-tile/CU) with the MFMA stream
// (~2500 cyc): each phase issues the NEXT phase's ds_reads BEFORE its own
// MFMA cluster; the compiler's counted lgkmcnt wait (operand dependence)
// lets the fresh reads stay outstanding across the MFMA.
//
// Phase = [barrier | stage DMA | issue reads(p+1) | sched_barrier |
//          (auto lgkm wait for frags(p)) | setprio(1) MFMA(p) setprio(0)]
// Quadrant order (r0c0, r0c1, r1c1, r1c0); frag regs: afA=r0, afB=r1,
// bf0 parity pair (read for t+1 at q3 while t's bf0 feeds q3's MFMA), bf1.
//
// DMA: A(t+1) both halves @q0 -> buf^1; B(t+2) both halves @q2 -> buf.
// ONE vmcnt(4) checkpoint at end of q2: drains A(t+1)+B(t+1) (needed by q3's
// prefetch reads of tile t+1), leaves B(t+2)x4 in flight. Never vmcnt(0)
// mid-loop. Hazard audit: every stage-write lands >= 2 barriers after the
// last read of its region completes (reads(p) complete before MFMA(p) via
// the operand wait; all waves pass barrier(p+1) only after MFMA(p)).
//
// XCD mapping (round-2, kept): XCD x owns tm in [4x,4x+4), sweeps tn ->
// A working set 2.6 MB, L2-pinned, 15x reuse. FETCH measured at ideal 59 MB.
// Swizzle (rule #21, kept): LDS dest linear; source pre-permuted
// lg = pg ^ (row&7); reads apply the same involution. Bank conflicts = 0.
__global__ __launch_bounds__(512, 2) void gemm256_k(const _Float16* __restrict__ A,
                                                    const _Float16* __restrict__ BT,
                                                    const float* __restrict__ bias,
                                                    _Float16* __restrict__ Qf,
                                                    _Float16* __restrict__ Kf,
                                                    _Float16* __restrict__ VTf) {
  __shared__ _Float16 sA[2][2][128 * 64];  // [buf][half][row*64 + col], 64 KB
  __shared__ _Float16 sB[2][2][128 * 64];  // 64 KB
  const int tid = threadIdx.x;
  const int wave = tid >> 6, lane = tid & 63;
  const int quad = lane >> 4, l16 = lane & 15;
  const int wm = wave >> 2, wn = wave & 3;      // wave grid 2M x 4N
  const int bh = wn >> 1, brb = (wn & 1) * 64;  // B half + row base within half
  const int KD = 1280, NT = 20;                 // 20 K-tiles of 64

  // A-pinned XCD mapping
  const int id = blockIdx.x;
  const int xcd = id & 7;
  const int qq = (id >> 3) & 3;
  const int tn = id >> 5;           // 0..14
  const int tm = xcd * 4 + qq;      // 0..31
  const int m0 = tm * 256, n0 = tn * 256;

  f32x4 acc[8][4] = {};

  // stage a full 256x64 operand tile (32 KB) in 4 DMA rounds (both halves)
  auto stageA2 = [&](int buf, int kt) {
#pragma unroll
    for (int c = 0; c < 4; ++c) {
      const int s = c * 512 + wave * 64 + lane;
      const int row = s >> 3;                 // 0..255 spans both halves
      const int lg = (s & 7) ^ (row & 7);
      async16(A + (size_t)(m0 + row) * KD + kt * 64 + lg * 8,
              &sA[buf][0][(size_t)(c * 512 + wave * 64) * 8]);
    }
  };
  auto stageB2 = [&](int buf, int kt) {
#pragma unroll
    for (int c = 0; c < 4; ++c) {
      const int s = c * 512 + wave * 64 + lane;
      const int row = s >> 3;
      const int lg = (s & 7) ^ (row & 7);
      async16(BT + (size_t)(n0 + row) * KD + kt * 64 + lg * 8,
              &sB[buf][0][(size_t)(c * 512 + wave * 64) * 8]);
    }
  };
  // A fragments: 4 row-frags x 2 ksteps from row-half rh of this wave's A-half
  auto ldA = [&](half8* af, const _Float16* hp, int rh) {
#pragma unroll
    for (int i = 0; i < 4; ++i)
#pragma unroll
      for (int kk = 0; kk < 2; ++kk) {
        const int lrow = rh * 64 + i * 16 + l16;
        const int pg = (kk * 4 + quad) ^ (l16 & 7);
        af[i * 2 + kk] = *(const half8*)(hp + lrow * 64 + pg * 8);
      }
  };
  // B fragments: 2 col-frags x 2 ksteps from col-half ch
  auto ldBh = [&](half8* bf, const _Float16* hp, int ch) {
#pragma unroll
    for (int j = 0; j < 2; ++j)
#pragma unroll
      for (int kk = 0; kk < 2; ++kk) {
        const int brow = brb + ch * 32 + j * 16 + l16;
        const int pg = (kk * 4 + quad) ^ (l16 & 7);
        bf[j * 2 + kk] = *(const half8*)(hp + brow * 64 + pg * 8);
      }
  };
  // one C-quadrant: 16 MFMA
  auto mmaq = [&](int r, int c, const half8* af, const half8* bf) {
#pragma unroll
    for (int i = 0; i < 4; ++i)
#pragma unroll
      for (int j = 0; j < 2; ++j)
#pragma unroll
        for (int kk = 0; kk < 2; ++kk)
          acc[r * 4 + i][c * 2 + j] =
              MFMA(af[i * 2 + kk], bf[j * 2 + kk], acc[r * 4 + i][c * 2 + j]);
  };

  const _Float16* aP[2] = {&sA[0][wm][0], &sA[1][wm][0]};
  const _Float16* bP[2] = {&sB[0][bh][0], &sB[1][bh][0]};

  // prologue: tile0 A+B, tile1 B (steady-state: B(t+1) was staged @q2(t-1));
  // vmcnt(4) drains tile0, leaves B(t1)x4 in flight.
  stageA2(0, 0);
  stageB2(0, 0);
  stageB2(1, 1);
  asm volatile("s_waitcnt vmcnt(4)" ::: "memory");
  __builtin_amdgcn_s_barrier();
  FENCE();
  __builtin_amdgcn_sched_barrier(0);

  half8 afA[8], afB[8], bf0a[4], bf0b[4], bf1[4];
  ldA(afA, aP[0], 0);       // q0(t0) frags, outstanding into the loop
  ldBh(bf0a, bP[0], 0);

  // tile body; buf passed as literal so LDS indexing constant-folds;
  // bf0 parity via explicit cur/next pointers (all frag indices static).
  auto tile = [&](int t, int buf, half8* bf0c, half8* bf0n) {
    const _Float16* aH = aP[buf];
    const _Float16* bH = bP[buf];

    // ---- q0: MFMA(r0,c0) w/ afA, bf0c; stage A(t+1); prefetch bf1
    PHB();
    if (t + 1 < NT) stageA2(buf ^ 1, t + 1);
    ldBh(bf1, bH, 1);
    __builtin_amdgcn_sched_barrier(0);
    __builtin_amdgcn_s_setprio(1);
    mmaq(0, 0, afA, bf0c);
    __builtin_amdgcn_s_setprio(0);

    // ---- q1: MFMA(r0,c1) w/ afA, bf1; prefetch afB (r1)
    PHB();
    ldA(afB, aH, 1);
    __builtin_amdgcn_sched_barrier(0);
    __builtin_amdgcn_s_setprio(1);
    mmaq(0, 1, afA, bf1);
    __builtin_amdgcn_s_setprio(0);

    // ---- q2: MFMA(r1,c1) w/ afB, bf1; stage B(t+2); K-tile vmcnt checkpoint
    PHB();
    if (t + 2 < NT) stageB2(buf, t + 2);
    __builtin_amdgcn_sched_barrier(0);
    __builtin_amdgcn_s_setprio(1);
    mmaq(1, 1, afB, bf1);
    __builtin_amdgcn_s_setprio(0);
    __builtin_amdgcn_sched_barrier(0);
    if (t < NT - 2)
      asm volatile("s_waitcnt vmcnt(4)" ::: "memory");  // counted, never 0
    else if (t == NT - 2)
      asm volatile("s_waitcnt vmcnt(0)" ::: "memory");  // final drain

    // ---- q3: MFMA(r1,c0) w/ afB, bf0c; prefetch t+1's q0 frags (afA, bf0n)
    PHB();
    if (t + 1 < NT) {
      ldA(afA, aP[buf ^ 1], 0);
      ldBh(bf0n, bP[buf ^ 1], 0);
    }
    __builtin_amdgcn_sched_barrier(0);
    __builtin_amdgcn_s_setprio(1);
    mmaq(1, 0, afB, bf0c);
    __builtin_amdgcn_s_setprio(0);
  };

  for (int t2 = 0; t2 < NT; t2 += 2) {
    tile(t2, 0, bf0a, bf0b);
    tile(t2 + 1, 1, bf0b, bf0a);
  }

  // scatter epilogue: C row = quad*4+reg, col = l16 within fragment [m89-verified]
#pragma unroll
  for (int ridx = 0; ridx < 8; ++ridx) {
#pragma unroll
    for (int cidx = 0; cidx < 4; ++cidx) {
      const int col = n0 + wn * 64 + cidx * 16 + l16;
      const float bv = bias[col];
      const int rowb = m0 + wm * 128 + ridx * 16 + quad * 4;
      const int which = col / 1280;
      const int rem = col - which * 1280;
      const int h = rem / 80;
      const int kk = rem - h * 80;
#pragma unroll
      for (int r = 0; r < 4; ++r) {
        const float v = acc[ridx][cidx][r] + bv;
        const int mrow = rowb + r;
        const int s = mrow >> 9, l = mrow & 511;
        const int shh = s * 16 + h;
        if (which == 0)
          Qf[((size_t)shh * 512 + l) * 96 + kk] = (_Float16)v;
        else if (which == 1)
          Kf[((size_t)shh * 512 + l) * 96 + kk] = (_Float16)v;
        else
          VTf[((size_t)shh * 80 + kk) * 512 + l] = (_Float16)v;
      }
    }
  }
}

// ---------------- GEMM1: 128x128 tile (proj): Out fp32 = A * projT^T + bias --
__global__ __launch_bounds__(256) void gemm_k(const _Float16* __restrict__ A,
                                              const _Float16* __restrict__ BT,
                                              const float* __restrict__ bias,
                                              float* __restrict__ Out) {
  __shared__ _Float16 sA[128 * 32];
  __shared__ _Float16 sB[128 * 32];
  const int tid = threadIdx.x;
  const int wave = tid >> 6, lane = tid & 63;
  const int quad = lane >> 4, l16 = lane & 15;
  const int m0 = blockIdx.x * 128;
  const int n0 = blockIdx.y * 128;
  const int mw = (wave & 1) * 64, nw = (wave >> 1) * 64;
  const int KD = 1280;

  const int srcg = (lane & 3) ^ ((lane >> 3) & 3);
  const int rg = (quad ^ ((l16 >> 1) & 3)) * 8;

  f32x4 acc[4][4] = {};

  for (int kt = 0; kt < KD; kt += 32) {
#pragma unroll
    for (int c = 0; c < 2; ++c) {
      const int j = wave * 2 + c;
      const int row = j * 16 + (lane >> 2);
      async16(A + (size_t)(m0 + row) * KD + kt + srcg * 8, &sA[j * 512]);
      async16(BT + (size_t)(n0 + row) * KD + kt + srcg * 8, &sB[j * 512]);
    }
    __syncthreads();
    half8 af[4], bf[4];
#pragma unroll
    for (int i = 0; i < 4; ++i) {
      af[i] = *(const half8*)&sA[(mw + i * 16 + l16) * 32 + rg];
      bf[i] = *(const half8*)&sB[(nw + i * 16 + l16) * 32 + rg];
    }
#pragma unroll
    for (int i = 0; i < 4; ++i)
#pragma unroll
      for (int j2 = 0; j2 < 4; ++j2)
        acc[i][j2] = MFMA(af[i], bf[j2], acc[i][j2]);
    __syncthreads();
  }

#pragma unroll
  for (int i = 0; i < 4; ++i) {
#pragma unroll
    for (int j2 = 0; j2 < 4; ++j2) {
      const int col = n0 + nw + j2 * 16 + l16;
      const float bv = bias[col];
      const int rowb = m0 + mw + i * 16 + quad * 4;
#pragma unroll
      for (int r = 0; r < 4; ++r)
        Out[(size_t)(rowb + r) * 1280 + col] = acc[i][j2][r] + bv;
    }
  }
}

// ---------------- RoPE in-place on Qf/Kf + zero the k-pad [80,96) -------------
__global__ __launch_bounds__(256) void rope_k(_Float16* __restrict__ Qf,
                                              _Float16* __restrict__ Kf,
                                              const float* __restrict__ cosNK,
                                              const float* __restrict__ sinNK) {
  const int gid = blockIdx.x * 256 + threadIdx.x;
  const int j = gid & 63;
  const int row = gid >> 6;
  const int qk = row >> 17;
  const int r = row & 131071;      // (s*16+h)*512 + l
  _Float16* buf = qk ? Kf : Qf;
  const int l = r & 511;
  const int s = r >> 13;
  const int t = s * 512 + l;
  const size_t base = (size_t)r * 96;
  if (j < 40) {
    const float v1 = (float)buf[base + j];
    const float v2 = (float)buf[base + j + 40];
    const float c1 = cosNK[t * 80 + j], s1 = sinNK[t * 80 + j];
    const float c2 = cosNK[t * 80 + j + 40], s2 = sinNK[t * 80 + j + 40];
    buf[base + j] = (_Float16)(v1 * c1 - v2 * s1);
    buf[base + j + 40] = (_Float16)(v2 * c2 + v1 * s2);
  } else if (j < 56) {
    buf[base + 40 + j] = (_Float16)0.f;  // kk = 80..95
  }
}

// ---------------- flash attention (S^T form, no-max softmax, sum via ones) ----
__global__ __launch_bounds__(256) void attn_k(const _Float16* __restrict__ Qf,
                                              const _Float16* __restrict__ Kf,
                                              const _Float16* __restrict__ VTf,
                                              _Float16* __restrict__ attnA) {
  __shared__ _Float16 sP[128 * 72];   // P tile, row stride 72
  __shared__ _Float16 sK[64 * 104];   // K tile, row stride 104 (conflict-free)
  __shared__ _Float16 sV[96 * 72];    // rows 0..79: V^T tile; rows 80..95: ones
  const int tid = threadIdx.x;
  const int wave = tid >> 6, lane = tid & 63;
  const int quad = lane >> 4, l16 = lane & 15;
  const int shh = blockIdx.x;  // s*16+h
  const int qt = blockIdx.y;   // 0..3
  const int h = shh & 15;
  const int s = shh >> 4;

  const _Float16* Qb = Qf + ((size_t)shh * 512 + qt * 128) * 96;
  const _Float16* Kb0 = Kf + (size_t)shh * 512 * 96;
  const _Float16* Vb0 = VTf + (size_t)shh * 80 * 512;

  // Q fragments straight from global (rows are lane-exact), pre-scaled
  const _Float16 c1h = (_Float16)(ATT_SCALE * LOG2E);
  half8 qf[2][3];
#pragma unroll
  for (int rt = 0; rt < 2; ++rt)
#pragma unroll
    for (int ks = 0; ks < 3; ++ks) {
      half8 t = *(const half8*)(Qb + (size_t)(wave * 32 + rt * 16 + l16) * 96 +
                                ks * 32 + quad * 8);
#pragma unroll
      for (int e = 0; e < 8; ++e) t[e] *= c1h;
      qf[rt][ks] = t;
    }

  // ones rows for the row-sum trick
  for (int idx = tid; idx < 16 * 72; idx += 256) sV[80 * 72 + idx] = (_Float16)1.f;

  f32x4 o[2][6] = {};  // ft 0..4: output features; ft 5: row sum

  for (int kc = 0; kc < 8; ++kc) {
    __syncthreads();  // prev iter LDS reads done (iter0: ones visible)
    // K tile -> sK, padded stride 104 halves (208 B), masked DMA (13 chunks)
    const _Float16* Kb = Kb0 + (size_t)kc * 64 * 96;
#pragma unroll
    for (int c = 0; c < 4; ++c) {
      const int j = wave + 4 * c;
      if (j < 13) {
        const int off = j * 1024 + lane * 16;  // LDS byte offset
        const int krow = off / 208;
        const int kcol = off - krow * 208;     // bytes within padded row
        if (kcol < 192)
          async16(Kb + (size_t)krow * 96 + (kcol >> 1), &sK[j * 512]);
      }
    }
    // V^T tile -> sV, padded stride 72 halves (144 B), masked DMA (12 chunks)
#pragma unroll
    for (int c = 0; c < 3; ++c) {
      const int j = wave + 4 * c;
      const int off = j * 1024 + lane * 16;
      const int vrow = off / 144;
      const int colb = off - vrow * 144;
      if (vrow < 80 && colb < 128)
        async16(Vb0 + (size_t)vrow * 512 + kc * 64 + (colb >> 1), &sV[j * 512]);
    }
    __syncthreads();

    // S^T = K Q^T (operand swap): lane holds S[q=l16][k=mt*16+quad*4+r]
    f32x4 sacc[2][4] = {};  // [rt][mt]
#pragma unroll
    for (int mt = 0; mt < 4; ++mt) {
#pragma unroll
      for (int ks = 0; ks < 3; ++ks) {
        half8 kb = *(const half8*)&sK[(mt * 16 + l16) * 104 + ks * 32 + quad * 8];
        sacc[0][mt] = MFMA(kb, qf[0][ks], sacc[0][mt]);
        sacc[1][mt] = MFMA(kb, qf[1][ks], sacc[1][mt]);
      }
    }

    // p = exp2(s), packed pairs (consecutive k!), one b64 store per (rt,mt)
#pragma unroll
    for (int rt = 0; rt < 2; ++rt) {
#pragma unroll
      for (int mt = 0; mt < 4; ++mt) {
        union { fp16x2 h2[2]; half4v h4; } u;
        u.h2[0] = __builtin_amdgcn_cvt_pkrtz(
            __builtin_amdgcn_exp2f(sacc[rt][mt][0]),
            __builtin_amdgcn_exp2f(sacc[rt][mt][1]));
        u.h2[1] = __builtin_amdgcn_cvt_pkrtz(
            __builtin_amdgcn_exp2f(sacc[rt][mt][2]),
            __builtin_amdgcn_exp2f(sacc[rt][mt][3]));
        *(half4v*)&sP[(wave * 32 + rt * 16 + l16) * 72 + mt * 16 + quad * 4] = u.h4;
      }
    }
    // sP rows are wave-private: per-wave LDS ordering suffices, no barrier

    // O += P V  (ft=5 accumulates the row sum via the ones rows)
#pragma unroll
    for (int ks = 0; ks < 2; ++ks) {
      half8 pa[2];
      pa[0] = *(const half8*)&sP[(wave * 32 + 0 + l16) * 72 + ks * 32 + quad * 8];
      pa[1] = *(const half8*)&sP[(wave * 32 + 16 + l16) * 72 + ks * 32 + quad * 8];
#pragma unroll
      for (int ft = 0; ft < 6; ++ft) {
        half8 vb = *(const half8*)&sV[(ft * 16 + l16) * 72 + ks * 32 + quad * 8];
        o[0][ft] = MFMA(pa[0], vb, o[0][ft]);
        o[1][ft] = MFMA(pa[1], vb, o[1][ft]);
      }
    }
  }

  // epilogue: divide by row sum, store fp16 into attnA [token][h*80+f]
#pragma unroll
  for (int rt = 0; rt < 2; ++rt) {
#pragma unroll
    for (int r = 0; r < 4; ++r) {
      const float inv = 1.0f / o[rt][5][r];
      const int token = s * 512 + qt * 128 + wave * 32 + rt * 16 + quad * 4 + r;
#pragma unroll
      for (int ft = 0; ft < 5; ++ft)
        attnA[(size_t)token * 1280 + h * 80 + ft * 16 + l16] =
            (_Float16)(o[rt][ft][r] * inv);
    }
  }
}

extern "C" void kernel_launch(void* const* d_in, const int* in_sizes, int n_in,
                              void* d_out, int out_size, void* d_ws, size_t ws_size,
                              hipStream_t stream) {
  (void)in_sizes; (void)n_in; (void)out_size; (void)ws_size;
  const float* hidden = (const float*)d_in[0];
  const float* cosNK = (const float*)d_in[2];
  const float* sinNK = (const float*)d_in[3];
  const float* qkv_w = (const float*)d_in[4];
  const float* qkv_b = (const float*)d_in[5];
  const float* proj_w = (const float*)d_in[6];
  const float* proj_b = (const float*)d_in[7];
  float* out = (float*)d_out;

  char* ws = (char*)d_ws;
  _Float16* hA    = (_Float16*)(ws);                   // 8192x1280        20971520 B
  _Float16* wT    = (_Float16*)(ws + 20971520);        // 3840x1280         9830400 B
  _Float16* projT = (_Float16*)(ws + 30801920);        // 1280x1280         3276800 B
  _Float16* Qf    = (_Float16*)(ws + 34078720);        // 256x512x96       25165824 B
  _Float16* Kf    = (_Float16*)(ws + 59244544);        // 256x512x96       25165824 B
  _Float16* VTf   = (_Float16*)(ws + 84410368);        // 256x80x512       20971520 B
  _Float16* attnA = (_Float16*)(ws + 105381888);       // 8192x1280        20971520 B

  cvt_k<<<10240, 256, 0, stream>>>(hidden, hA, 2621440);
  transpose_cvt_k<<<dim3(120, 40), 256, 0, stream>>>(qkv_w, wT, 1280, 3840);
  transpose_cvt_k<<<dim3(40, 40), 256, 0, stream>>>(proj_w, projT, 1280, 1280);
  gemm256_k<<<480, 512, 0, stream>>>(hA, wT, qkv_b, Qf, Kf, VTf);
  rope_k<<<65536, 256, 0, stream>>>(Qf, Kf, cosNK, sinNK);
  attn_k<<<dim3(256, 4), 256, 0, stream>>>(Qf, Kf, VTf, attnA);
  gemm_k<<<dim3(64, 10), 256, 0, stream>>>(attnA, projT, proj_b, out);
}

// Round 4
// 353.958 us; speedup vs baseline: 1.1971x; 1.1971x over previous
//
#include <hip/hip_runtime.h>

// Problem constants (fixed shape)
// N=8192 tokens, D=1280, H=16 heads, K=80 head dim (pad 96), S=16 segs, L=512
#define LOG2E 1.44269504088896340736f
#define ATT_SCALE 0.11180339887498949f  // 80^-0.5

typedef _Float16 half8 __attribute__((ext_vector_type(8)));
typedef _Float16 half4v __attribute__((ext_vector_type(4)));
typedef __fp16 fp16x2 __attribute__((ext_vector_type(2)));
typedef float f32x4 __attribute__((ext_vector_type(4)));

#define MFMA(a, b, c) __builtin_amdgcn_mfma_f32_16x16x32_f16((a), (b), (c), 0, 0, 0)

__device__ __forceinline__ void async16(const _Float16* g, _Float16* l) {
  __builtin_amdgcn_global_load_lds(
      (const __attribute__((address_space(1))) unsigned int*)g,
      (__attribute__((address_space(3))) unsigned int*)l,
      16, 0, 0);
}

#define FENCE() asm volatile("" ::: "memory")
// ONE barrier per phase. Memory fence only (keeps LDS/DMA ops on the right
// side); NO sched_barrier(0), NO lgkmcnt(0): register-only MFMA may cross,
// so the compiler can software-pipeline MFMA(p) under reads(p+1) (m141
// lesson: order-pinning cost −42% on the m97 structure). Correctness: each
// wave's ds_reads are drained by the compiler's auto-lgkm wait before its
// own MFMA, hence before it arrives at the next barrier — so by the time
// any wave issues a DMA after barrier(p+1), all reads from phase p have
// completed. vmcnt checkpoints are collective because each wave's vmcnt
// precedes its barrier arrival.
#define PHB()                                   \
  do {                                          \
    FENCE();                                    \
    __builtin_amdgcn_s_barrier();               \
    FENCE();                                    \
  } while (0)

// ---------------- fp32 -> fp16 convert (hidden) ----------------
__global__ __launch_bounds__(256) void cvt_k(const float* __restrict__ in,
                                             _Float16* __restrict__ out, int n4) {
  int i = blockIdx.x * 256 + threadIdx.x;
  if (i < n4) {
    f32x4 v = ((const f32x4*)in)[i];
    half4v hv;
    hv[0] = (_Float16)v[0]; hv[1] = (_Float16)v[1];
    hv[2] = (_Float16)v[2]; hv[3] = (_Float16)v[3];
    ((half4v*)out)[i] = hv;
  }
}

// ---------------- transpose + convert: in R x C fp32 -> out C x R fp16 ----------
__global__ __launch_bounds__(256) void transpose_cvt_k(const float* __restrict__ in,
                                                       _Float16* __restrict__ out,
                                                       int R, int C) {
  __shared__ float tile[32][33];
  const int tx = threadIdx.x & 31, ty = threadIdx.x >> 5;
  const int c0 = blockIdx.x * 32, r0 = blockIdx.y * 32;
#pragma unroll
  for (int i = 0; i < 32; i += 8)
    tile[ty + i][tx] = in[(size_t)(r0 + ty + i) * C + c0 + tx];
  __syncthreads();
#pragma unroll
  for (int i = 0; i < 32; i += 8)
    out[(size_t)(c0 + ty + i) * R + r0 + tx] = (_Float16)tile[tx][ty + i];
}

// ---------------- GEMM0: 256x256 tile, BK=64, 4-phase K-loop, de-pinned ------
// C = A(8192x1280) * BT^T (3840x1280), scatter epilogue -> Qf/Kf/VTf
//
// Round-4 = round-2 schedule (proven 119.6 us / 28%) with the scheduling
// pins removed: 1 raw barrier per phase, no lgkmcnt(0), no sched_barrier(0).
// The compiler's auto-inserted counted lgkm waits + free motion of
// register-only MFMA across the fences supply the MFMA||ds_read overlap
// that the pinned version serialized. No source-level fragment double
// buffering (round-3 spilled: WRITE +31MB scratch).
//
// Per tile t (buf = t&1; 20 tiles of BK=64):
//   q0: BAR; read afA(r0) 8 + bf0 4; stage A(t+1) h0; MFMA(r0,c0)
//   q1: BAR; read bf1 4;             stage A(t+1) h1; MFMA(r0,c1)
//   q2: BAR; read af(r1) 8;          stage B(t+2) h0; MFMA(r1,c1)
//   q3: BAR;                         stage B(t+2) h1; vmcnt(4); MFMA(r1,c0)
// vmcnt(4) drains A(t+1)+B(t+1) (8 oldest), leaves B(t+2)x4 in flight —
// counted, never 0 mid-loop (T4). Hazard audit (1-barrier phases): every
// DMA write in phase p+1 targets a region whose last reads drained in
// phase <= p (before each reader's own MFMA -> before its barrier arrival).
//
// XCD mapping (round-2, kept): XCD x owns tm in [4x,4x+4), sweeps tn ->
// A working set 2.6 MB, L2-pinned, 15x reuse. FETCH measured at ideal 59 MB.
// Swizzle (rule #21, kept): LDS dest linear; source pre-permuted
// lg = pg ^ (row&7); reads apply the same involution. Bank conflicts = 0.
__global__ __launch_bounds__(512, 2) void gemm256_k(const _Float16* __restrict__ A,
                                                    const _Float16* __restrict__ BT,
                                                    const float* __restrict__ bias,
                                                    _Float16* __restrict__ Qf,
                                                    _Float16* __restrict__ Kf,
                                                    _Float16* __restrict__ VTf) {
  __shared__ _Float16 sA[2][2][128 * 64];  // [buf][half][row*64 + col], 64 KB
  __shared__ _Float16 sB[2][2][128 * 64];  // 64 KB
  const int tid = threadIdx.x;
  const int wave = tid >> 6, lane = tid & 63;
  const int quad = lane >> 4, l16 = lane & 15;
  const int wm = wave >> 2, wn = wave & 3;      // wave grid 2M x 4N
  const int bh = wn >> 1, brb = (wn & 1) * 64;  // B half + row base within half
  const int KD = 1280, NT = 20;                 // 20 K-tiles of 64

  // A-pinned XCD mapping
  const int id = blockIdx.x;
  const int xcd = id & 7;
  const int qq = (id >> 3) & 3;
  const int tn = id >> 5;           // 0..14
  const int tm = xcd * 4 + qq;      // 0..31
  const int m0 = tm * 256, n0 = tn * 256;

  f32x4 acc[8][4] = {};

  // stage one half-tile (128 rows x 64 cols fp16 = 16 KB) in 2 DMA rounds.
  // slot s = c*512 + wave*64 + lane; LDS dest linear; source carries swizzle.
  auto stageA = [&](int buf, int half, int kt) {
#pragma unroll
    for (int c = 0; c < 2; ++c) {
      const int s = c * 512 + wave * 64 + lane;
      const int row = s >> 3;
      const int lg = (s & 7) ^ (row & 7);
      async16(A + (size_t)(m0 + half * 128 + row) * KD + kt * 64 + lg * 8,
              &sA[buf][half][(size_t)(c * 512 + wave * 64) * 8]);
    }
  };
  auto stageB = [&](int buf, int half, int kt) {
#pragma unroll
    for (int c = 0; c < 2; ++c) {
      const int s = c * 512 + wave * 64 + lane;
      const int row = s >> 3;
      const int lg = (s & 7) ^ (row & 7);
      async16(BT + (size_t)(n0 + half * 128 + row) * KD + kt * 64 + lg * 8,
              &sB[buf][half][(size_t)(c * 512 + wave * 64) * 8]);
    }
  };
  // A fragments: 4 row-frags x 2 ksteps from row-half rh of this wave's A-half
  auto ldA = [&](half8* af, const _Float16* hp, int rh) {
#pragma unroll
    for (int i = 0; i < 4; ++i)
#pragma unroll
      for (int kk = 0; kk < 2; ++kk) {
        const int lrow = rh * 64 + i * 16 + l16;
        const int pg = (kk * 4 + quad) ^ (l16 & 7);
        af[i * 2 + kk] = *(const half8*)(hp + lrow * 64 + pg * 8);
      }
  };
  // B fragments: 2 col-frags x 2 ksteps from col-half ch
  auto ldB = [&](half8* bf, const _Float16* hp, int ch) {
#pragma unroll
    for (int j = 0; j < 2; ++j)
#pragma unroll
      for (int kk = 0; kk < 2; ++kk) {
        const int brow = brb + ch * 32 + j * 16 + l16;
        const int pg = (kk * 4 + quad) ^ (l16 & 7);
        bf[j * 2 + kk] = *(const half8*)(hp + brow * 64 + pg * 8);
      }
  };
  // one C-quadrant: 16 MFMA
  auto mmaq = [&](int r, int c, const half8* af, const half8* bf) {
#pragma unroll
    for (int i = 0; i < 4; ++i)
#pragma unroll
      for (int j = 0; j < 2; ++j)
#pragma unroll
        for (int kk = 0; kk < 2; ++kk)
          acc[r * 4 + i][c * 2 + j] =
              MFMA(af[i * 2 + kk], bf[j * 2 + kk], acc[r * 4 + i][c * 2 + j]);
  };

  // prologue: tile0 A+B, tile1 B; vmcnt(4) leaves B(t1)x4 in flight.
  // (q0's barrier makes the drain collective before any reads.)
  stageA(0, 0, 0); stageA(0, 1, 0);
  stageB(0, 0, 0); stageB(0, 1, 0);
  stageB(1, 0, 1); stageB(1, 1, 1);
  asm volatile("s_waitcnt vmcnt(4)" ::: "memory");

  half8 af[8], bf0[4], bf1[4];
#pragma unroll 2
  for (int t = 0; t < NT; ++t) {
    const int buf = t & 1;
    const _Float16* aH = &sA[0][0][0] + buf * (2 * 128 * 64) + wm * (128 * 64);
    const _Float16* bH = &sB[0][0][0] + buf * (2 * 128 * 64) + bh * (128 * 64);

    // ---- q0: MFMA(r0,c0); stage A(t+1) h0
    PHB();
    ldA(af, aH, 0);
    ldB(bf0, bH, 0);
    if (t + 1 < NT) stageA(buf ^ 1, 0, t + 1);
    __builtin_amdgcn_s_setprio(1);
    mmaq(0, 0, af, bf0);
    __builtin_amdgcn_s_setprio(0);

    // ---- q1: MFMA(r0,c1); stage A(t+1) h1
    PHB();
    ldB(bf1, bH, 1);
    if (t + 1 < NT) stageA(buf ^ 1, 1, t + 1);
    __builtin_amdgcn_s_setprio(1);
    mmaq(0, 1, af, bf1);
    __builtin_amdgcn_s_setprio(0);

    // ---- q2: MFMA(r1,c1); stage B(t+2) h0 (sB[buf] reads finished in q1)
    PHB();
    ldA(af, aH, 1);
    if (t + 2 < NT) stageB(buf, 0, t + 2);
    __builtin_amdgcn_s_setprio(1);
    mmaq(1, 1, af, bf1);
    __builtin_amdgcn_s_setprio(0);

    // ---- q3: MFMA(r1,c0); stage B(t+2) h1; K-tile vmcnt checkpoint
    PHB();
    if (t + 2 < NT) stageB(buf, 1, t + 2);
    if (t == NT - 2)
      asm volatile("s_waitcnt vmcnt(0)" ::: "memory");  // final drain
    else if (t < NT - 2)
      asm volatile("s_waitcnt vmcnt(4)" ::: "memory");  // counted, never 0
    __builtin_amdgcn_s_setprio(1);
    mmaq(1, 0, af, bf0);
    __builtin_amdgcn_s_setprio(0);
  }

  // scatter epilogue: C row = quad*4+reg, col = l16 within fragment [m89-verified]
#pragma unroll
  for (int ridx = 0; ridx < 8; ++ridx) {
#pragma unroll
    for (int cidx = 0; cidx < 4; ++cidx) {
      const int col = n0 + wn * 64 + cidx * 16 + l16;
      const float bv = bias[col];
      const int rowb = m0 + wm * 128 + ridx * 16 + quad * 4;
      const int which = col / 1280;
      const int rem = col - which * 1280;
      const int h = rem / 80;
      const int kk = rem - h * 80;
#pragma unroll
      for (int r = 0; r < 4; ++r) {
        const float v = acc[ridx][cidx][r] + bv;
        const int mrow = rowb + r;
        const int s = mrow >> 9, l = mrow & 511;
        const int shh = s * 16 + h;
        if (which == 0)
          Qf[((size_t)shh * 512 + l) * 96 + kk] = (_Float16)v;
        else if (which == 1)
          Kf[((size_t)shh * 512 + l) * 96 + kk] = (_Float16)v;
        else
          VTf[((size_t)shh * 80 + kk) * 512 + l] = (_Float16)v;
      }
    }
  }
}

// ---------------- GEMM1: 128x128 tile (proj): Out fp32 = A * projT^T + bias --
__global__ __launch_bounds__(256) void gemm_k(const _Float16* __restrict__ A,
                                              const _Float16* __restrict__ BT,
                                              const float* __restrict__ bias,
                                              float* __restrict__ Out) {
  __shared__ _Float16 sA[128 * 32];
  __shared__ _Float16 sB[128 * 32];
  const int tid = threadIdx.x;
  const int wave = tid >> 6, lane = tid & 63;
  const int quad = lane >> 4, l16 = lane & 15;
  const int m0 = blockIdx.x * 128;
  const int n0 = blockIdx.y * 128;
  const int mw = (wave & 1) * 64, nw = (wave >> 1) * 64;
  const int KD = 1280;

  const int srcg = (lane & 3) ^ ((lane >> 3) & 3);
  const int rg = (quad ^ ((l16 >> 1) & 3)) * 8;

  f32x4 acc[4][4] = {};

  for (int kt = 0; kt < KD; kt += 32) {
#pragma unroll
    for (int c = 0; c < 2; ++c) {
      const int j = wave * 2 + c;
      const int row = j * 16 + (lane >> 2);
      async16(A + (size_t)(m0 + row) * KD + kt + srcg * 8, &sA[j * 512]);
      async16(BT + (size_t)(n0 + row) * KD + kt + srcg * 8, &sB[j * 512]);
    }
    __syncthreads();
    half8 af[4], bf[4];
#pragma unroll
    for (int i = 0; i < 4; ++i) {
      af[i] = *(const half8*)&sA[(mw + i * 16 + l16) * 32 + rg];
      bf[i] = *(const half8*)&sB[(nw + i * 16 + l16) * 32 + rg];
    }
#pragma unroll
    for (int i = 0; i < 4; ++i)
#pragma unroll
      for (int j2 = 0; j2 < 4; ++j2)
        acc[i][j2] = MFMA(af[i], bf[j2], acc[i][j2]);
    __syncthreads();
  }

#pragma unroll
  for (int i = 0; i < 4; ++i) {
#pragma unroll
    for (int j2 = 0; j2 < 4; ++j2) {
      const int col = n0 + nw + j2 * 16 + l16;
      const float bv = bias[col];
      const int rowb = m0 + mw + i * 16 + quad * 4;
#pragma unroll
      for (int r = 0; r < 4; ++r)
        Out[(size_t)(rowb + r) * 1280 + col] = acc[i][j2][r] + bv;
    }
  }
}

// ---------------- RoPE in-place on Qf/Kf + zero the k-pad [80,96) -------------
__global__ __launch_bounds__(256) void rope_k(_Float16* __restrict__ Qf,
                                              _Float16* __restrict__ Kf,
                                              const float* __restrict__ cosNK,
                                              const float* __restrict__ sinNK) {
  const int gid = blockIdx.x * 256 + threadIdx.x;
  const int j = gid & 63;
  const int row = gid >> 6;
  const int qk = row >> 17;
  const int r = row & 131071;      // (s*16+h)*512 + l
  _Float16* buf = qk ? Kf : Qf;
  const int l = r & 511;
  const int s = r >> 13;
  const int t = s * 512 + l;
  const size_t base = (size_t)r * 96;
  if (j < 40) {
    const float v1 = (float)buf[base + j];
    const float v2 = (float)buf[base + j + 40];
    const float c1 = cosNK[t * 80 + j], s1 = sinNK[t * 80 + j];
    const float c2 = cosNK[t * 80 + j + 40], s2 = sinNK[t * 80 + j + 40];
    buf[base + j] = (_Float16)(v1 * c1 - v2 * s1);
    buf[base + j + 40] = (_Float16)(v2 * c2 + v1 * s2);
  } else if (j < 56) {
    buf[base + 40 + j] = (_Float16)0.f;  // kk = 80..95
  }
}

// ---------------- flash attention (S^T form, no-max softmax, sum via ones) ----
__global__ __launch_bounds__(256) void attn_k(const _Float16* __restrict__ Qf,
                                              const _Float16* __restrict__ Kf,
                                              const _Float16* __restrict__ VTf,
                                              _Float16* __restrict__ attnA) {
  __shared__ _Float16 sP[128 * 72];   // P tile, row stride 72
  __shared__ _Float16 sK[64 * 104];   // K tile, row stride 104 (conflict-free)
  __shared__ _Float16 sV[96 * 72];    // rows 0..79: V^T tile; rows 80..95: ones
  const int tid = threadIdx.x;
  const int wave = tid >> 6, lane = tid & 63;
  const int quad = lane >> 4, l16 = lane & 15;
  const int shh = blockIdx.x;  // s*16+h
  const int qt = blockIdx.y;   // 0..3
  const int h = shh & 15;
  const int s = shh >> 4;

  const _Float16* Qb = Qf + ((size_t)shh * 512 + qt * 128) * 96;
  const _Float16* Kb0 = Kf + (size_t)shh * 512 * 96;
  const _Float16* Vb0 = VTf + (size_t)shh * 80 * 512;

  // Q fragments straight from global (rows are lane-exact), pre-scaled
  const _Float16 c1h = (_Float16)(ATT_SCALE * LOG2E);
  half8 qf[2][3];
#pragma unroll
  for (int rt = 0; rt < 2; ++rt)
#pragma unroll
    for (int ks = 0; ks < 3; ++ks) {
      half8 t = *(const half8*)(Qb + (size_t)(wave * 32 + rt * 16 + l16) * 96 +
                                ks * 32 + quad * 8);
#pragma unroll
      for (int e = 0; e < 8; ++e) t[e] *= c1h;
      qf[rt][ks] = t;
    }

  // ones rows for the row-sum trick
  for (int idx = tid; idx < 16 * 72; idx += 256) sV[80 * 72 + idx] = (_Float16)1.f;

  f32x4 o[2][6] = {};  // ft 0..4: output features; ft 5: row sum

  for (int kc = 0; kc < 8; ++kc) {
    __syncthreads();  // prev iter LDS reads done (iter0: ones visible)
    // K tile -> sK, padded stride 104 halves (208 B), masked DMA (13 chunks)
    const _Float16* Kb = Kb0 + (size_t)kc * 64 * 96;
#pragma unroll
    for (int c = 0; c < 4; ++c) {
      const int j = wave + 4 * c;
      if (j < 13) {
        const int off = j * 1024 + lane * 16;  // LDS byte offset
        const int krow = off / 208;
        const int kcol = off - krow * 208;     // bytes within padded row
        if (kcol < 192)
          async16(Kb + (size_t)krow * 96 + (kcol >> 1), &sK[j * 512]);
      }
    }
    // V^T tile -> sV, padded stride 72 halves (144 B), masked DMA (12 chunks)
#pragma unroll
    for (int c = 0; c < 3; ++c) {
      const int j = wave + 4 * c;
      const int off = j * 1024 + lane * 16;
      const int vrow = off / 144;
      const int colb = off - vrow * 144;
      if (vrow < 80 && colb < 128)
        async16(Vb0 + (size_t)vrow * 512 + kc * 64 + (colb >> 1), &sV[j * 512]);
    }
    __syncthreads();

    // S^T = K Q^T (operand swap): lane holds S[q=l16][k=mt*16+quad*4+r]
    f32x4 sacc[2][4] = {};  // [rt][mt]
#pragma unroll
    for (int mt = 0; mt < 4; ++mt) {
#pragma unroll
      for (int ks = 0; ks < 3; ++ks) {
        half8 kb = *(const half8*)&sK[(mt * 16 + l16) * 104 + ks * 32 + quad * 8];
        sacc[0][mt] = MFMA(kb, qf[0][ks], sacc[0][mt]);
        sacc[1][mt] = MFMA(kb, qf[1][ks], sacc[1][mt]);
      }
    }

    // p = exp2(s), packed pairs (consecutive k!), one b64 store per (rt,mt)
#pragma unroll
    for (int rt = 0; rt < 2; ++rt) {
#pragma unroll
      for (int mt = 0; mt < 4; ++mt) {
        union { fp16x2 h2[2]; half4v h4; } u;
        u.h2[0] = __builtin_amdgcn_cvt_pkrtz(
            __builtin_amdgcn_exp2f(sacc[rt][mt][0]),
            __builtin_amdgcn_exp2f(sacc[rt][mt][1]));
        u.h2[1] = __builtin_amdgcn_cvt_pkrtz(
            __builtin_amdgcn_exp2f(sacc[rt][mt][2]),
            __builtin_amdgcn_exp2f(sacc[rt][mt][3]));
        *(half4v*)&sP[(wave * 32 + rt * 16 + l16) * 72 + mt * 16 + quad * 4] = u.h4;
      }
    }
    // sP rows are wave-private: per-wave LDS ordering suffices, no barrier

    // O += P V  (ft=5 accumulates the row sum via the ones rows)
#pragma unroll
    for (int ks = 0; ks < 2; ++ks) {
      half8 pa[2];
      pa[0] = *(const half8*)&sP[(wave * 32 + 0 + l16) * 72 + ks * 32 + quad * 8];
      pa[1] = *(const half8*)&sP[(wave * 32 + 16 + l16) * 72 + ks * 32 + quad * 8];
#pragma unroll
      for (int ft = 0; ft < 6; ++ft) {
        half8 vb = *(const half8*)&sV[(ft * 16 + l16) * 72 + ks * 32 + quad * 8];
        o[0][ft] = MFMA(pa[0], vb, o[0][ft]);
        o[1][ft] = MFMA(pa[1], vb, o[1][ft]);
      }
    }
  }

  // epilogue: divide by row sum, store fp16 into attnA [token][h*80+f]
#pragma unroll
  for (int rt = 0; rt < 2; ++rt) {
#pragma unroll
    for (int r = 0; r < 4; ++r) {
      const float inv = 1.0f / o[rt][5][r];
      const int token = s * 512 + qt * 128 + wave * 32 + rt * 16 + quad * 4 + r;
#pragma unroll
      for (int ft = 0; ft < 5; ++ft)
        attnA[(size_t)token * 1280 + h * 80 + ft * 16 + l16] =
            (_Float16)(o[rt][ft][r] * inv);
    }
  }
}

extern "C" void kernel_launch(void* const* d_in, const int* in_sizes, int n_in,
                              void* d_out, int out_size, void* d_ws, size_t ws_size,
                              hipStream_t stream) {
  (void)in_sizes; (void)n_in; (void)out_size; (void)ws_size;
  const float* hidden = (const float*)d_in[0];
  const float* cosNK = (const float*)d_in[2];
  const float* sinNK = (const float*)d_in[3];
  const float* qkv_w = (const float*)d_in[4];
  const float* qkv_b = (const float*)d_in[5];
  const float* proj_w = (const float*)d_in[6];
  const float* proj_b = (const float*)d_in[7];
  float* out = (float*)d_out;

  char* ws = (char*)d_ws;
  _Float16* hA    = (_Float16*)(ws);                   // 8192x1280        20971520 B
  _Float16* wT    = (_Float16*)(ws + 20971520);        // 3840x1280         9830400 B
  _Float16* projT = (_Float16*)(ws + 30801920);        // 1280x1280         3276800 B
  _Float16* Qf    = (_Float16*)(ws + 34078720);        // 256x512x96       25165824 B
  _Float16* Kf    = (_Float16*)(ws + 59244544);        // 256x512x96       25165824 B
  _Float16* VTf   = (_Float16*)(ws + 84410368);        // 256x80x512       20971520 B
  _Float16* attnA = (_Float16*)(ws + 105381888);       // 8192x1280        20971520 B

  cvt_k<<<10240, 256, 0, stream>>>(hidden, hA, 2621440);
  transpose_cvt_k<<<dim3(120, 40), 256, 0, stream>>>(qkv_w, wT, 1280, 3840);
  transpose_cvt_k<<<dim3(40, 40), 256, 0, stream>>>(proj_w, projT, 1280, 1280);
  gemm256_k<<<480, 512, 0, stream>>>(hA, wT, qkv_b, Qf, Kf, VTf);
  rope_k<<<65536, 256, 0, stream>>>(Qf, Kf, cosNK, sinNK);
  attn_k<<<dim3(256, 4), 256, 0, stream>>>(Qf, Kf, VTf, attnA);
  gemm_k<<<dim3(64, 10), 256, 0, stream>>>(attnA, projT, proj_b, out);
}